// Round 5
// baseline (126.858 us; speedup 1.0000x reference)
//
#include <hip/hip_runtime.h>
#include <math.h>

#define BB 1024
#define LL 256
#define VV 50000
#define EE 300
#define AA 30
#define WORD_THRES 0.2f
#define COS_EPS_F 1e-8f
#define NEG_INF_F -1e9f

// ---------------------------------------------------------------------------
// Kernel 1: cent[v] = max_a ( (cos(a_emb[a], w_emb[v]) > thres ? cos : 0) * w[a] )
// Lane decomposition: 64 = 8 E-lanes (p) x 2 aspect-halves (ah, 15 each)
// x 4 row-slots; 4 rows/thread -> 64 rows/block, grid 782 (~3 blocks/CU
// co-resident vs round-4's 1.5 -> pipes actually overlap).
// Each ds_read_b128 of a_emb feeds 16 FMAs (4 rows x 4 components).
// ---------------------------------------------------------------------------
__global__ void __launch_bounds__(256) cent_kernel(
    const float* __restrict__ w_emb,     // [V, E]
    const float* __restrict__ a_emb,     // [A, E]
    const float* __restrict__ a_weight,  // [A]
    float* __restrict__ cent)            // [V]
{
    __shared__ float4 s_a[AA * 75];      // a-major: s_a[a*75 + j], 36000 B
    __shared__ float s_scale[AA];        // 1 / max(||a||, eps)
    __shared__ float s_aw[AA];

    const int t = threadIdx.x;
    const float4* __restrict__ a4 = (const float4*)a_emb;   // [A][75]

    // stage a_emb -> LDS (coalesced copy)
    for (int s = t; s < AA * 75; s += 256) s_a[s] = a4[s];

    // aspect norms: 8 lanes per aspect (in-wave groups)
    {
        const int a = t >> 3, j = t & 7;
        if (a < AA) {
            float n2a = 0.f;
            for (int c = j; c < 75; c += 8) {
                const float4 x = a4[a * 75 + c];
                n2a += x.x * x.x + x.y * x.y + x.z * x.z + x.w * x.w;
            }
            n2a += __shfl_xor(n2a, 1);
            n2a += __shfl_xor(n2a, 2);
            n2a += __shfl_xor(n2a, 4);
            if (j == 0) {
                s_scale[a] = 1.f / fmaxf(sqrtf(n2a), COS_EPS_F);
                s_aw[a] = a_weight[a];
            }
        }
    }
    __syncthreads();

    const int p    = t & 7;          // E-lane: float4 cols j = 8k + p
    const int ah   = (t >> 3) & 1;   // aspect half: aspects ah*15 .. ah*15+14
    const int slot = t >> 4;         // 16 row-slots per block
    const int a_base = ah * 15;

    const float* __restrict__ r[4];
    bool ok[4];
#pragma unroll
    for (int i = 0; i < 4; ++i) {
        const int v = blockIdx.x * 64 + slot + 16 * i;
        ok[i] = v < VV;
        r[i] = w_emb + (size_t)(ok[i] ? v : 0) * EE;
    }

    float acc[15][4];                // [aspect-in-half][row]
#pragma unroll
    for (int a = 0; a < 15; ++a)
#pragma unroll
        for (int i = 0; i < 4; ++i) acc[a][i] = 0.f;
    float n2[4] = {0.f, 0.f, 0.f, 0.f};

    for (int k = 0; k < 10; ++k) {
        const int j = 8 * k + p;
        if (j < 75) {
            float4 wv[4];
#pragma unroll
            for (int i = 0; i < 4; ++i) {
                wv[i] = *(const float4*)(r[i] + 4 * j);
                n2[i] += wv[i].x * wv[i].x + wv[i].y * wv[i].y +
                         wv[i].z * wv[i].z + wv[i].w * wv[i].w;
            }
            const float4* __restrict__ ap = s_a + a_base * 75 + j;
#pragma unroll
            for (int a = 0; a < 15; ++a) {
                const float4 av = ap[a * 75];    // 4-way broadcast, 2-way banks
#pragma unroll
                for (int i = 0; i < 4; ++i) {
                    acc[a][i] = fmaf(av.x, wv[i].x, fmaf(av.y, wv[i].y,
                                fmaf(av.z, wv[i].z, fmaf(av.w, wv[i].w, acc[a][i]))));
                }
            }
        }
    }

    // reduce across the 8 E-lanes (xor 1,2,4 stays inside the 8-lane group)
#pragma unroll
    for (int i = 0; i < 4; ++i) {
        n2[i] += __shfl_xor(n2[i], 1);
        n2[i] += __shfl_xor(n2[i], 2);
        n2[i] += __shfl_xor(n2[i], 4);
#pragma unroll
        for (int a = 0; a < 15; ++a) {
            acc[a][i] += __shfl_xor(acc[a][i], 1);
            acc[a][i] += __shfl_xor(acc[a][i], 2);
            acc[a][i] += __shfl_xor(acc[a][i], 4);
        }
    }

    // epilogue on p==0 lanes of both aspect halves, then combine via xor 8
    float m[4] = {0.f, 0.f, 0.f, 0.f};
#pragma unroll
    for (int i = 0; i < 4; ++i) {
        const float invx = 1.f / fmaxf(sqrtf(n2[i]), COS_EPS_F);
#pragma unroll
        for (int a = 0; a < 15; ++a) {
            const float cosv = acc[a][i] * s_scale[a_base + a] * invx;
            m[i] = fmaxf(m[i], (cosv > WORD_THRES) ? cosv * s_aw[a_base + a] : 0.f);
        }
    }
#pragma unroll
    for (int i = 0; i < 4; ++i) m[i] = fmaxf(m[i], __shfl_xor(m[i], 8));

    if (p == 0 && ah == 0) {
#pragma unroll
        for (int i = 0; i < 4; ++i)
            if (ok[i]) cent[blockIdx.x * 64 + slot + 16 * i] = m[i];
    }
}

// ---------------------------------------------------------------------------
// Kernel 2: one block per batch row. 3 barriers. Sparse z over the ~2-8
// active positions (a_l == 0 exactly for masked positions).
// ---------------------------------------------------------------------------
__global__ void __launch_bounds__(256) row_kernel(
    const int* __restrict__ inputs,   // [B, L]
    const float* __restrict__ w_emb,  // [V, E]
    const float* __restrict__ cent,   // [V]
    float* __restrict__ out)          // enc_out [B,E] | a [B,L] | cs [B]
{
    const int b = blockIdx.x;
    const int t = threadIdx.x;          // == l
    const int wid = t >> 6, lane = t & 63;

    __shared__ float pA[4], pB[4], pC[4], pD[4];
    __shared__ int s_nact;
    __shared__ int s_act_id[LL];
    __shared__ float s_act_w[LL];

    const int id = inputs[b * LL + t];
    const float c = cent[id];
    const float score = (c > 0.f) ? c : NEG_INF_F;
    const float cnt = (id != 0) ? 1.f : 0.f;
    if (t == 0) s_nact = 0;

    // fused sum(c) / sum(cnt) / max(score) in one shuffle pass
    float s1 = c, s2 = cnt, s3 = score;
#pragma unroll
    for (int o = 32; o > 0; o >>= 1) {
        s1 += __shfl_down(s1, o);
        s2 += __shfl_down(s2, o);
        s3 = fmaxf(s3, __shfl_down(s3, o));
    }
    if (lane == 0) { pA[wid] = s1; pB[wid] = s2; pC[wid] = s3; }
    __syncthreads();

    const float sum_c = pA[0] + pA[1] + pA[2] + pA[3];
    const float len   = pB[0] + pB[1] + pB[2] + pB[3];
    const float mx    = fmaxf(fmaxf(pC[0], pC[1]), fmaxf(pC[2], pC[3]));

    const float p = expf(score - mx);   // expf(-1e9)==0; all-masked row -> p=1
    float s4 = p;
#pragma unroll
    for (int o = 32; o > 0; o >>= 1) s4 += __shfl_down(s4, o);
    if (lane == 0) pD[wid] = s4;
    __syncthreads();
    const float sum_p = pD[0] + pD[1] + pD[2] + pD[3];

    const float a_l = p / sum_p;
    const float cs = sum_c / (len + 1e-5f);
    const float gate = (cs > 1e-4f) ? 1.f : 0.f;

    out[BB * EE + b * LL + t] = a_l;            // attention
    if (t == 0) out[BB * EE + BB * LL + b] = cs;

    if (score > -1e8f) {                         // active <=> cent > 0
        const int i = atomicAdd(&s_nact, 1);
        s_act_id[i] = id;
        s_act_w[i] = a_l;
    }
    __syncthreads();
    const int n = s_nact;

    // z over active entries only; thread t<75 owns float4 column t
    if (t < EE / 4) {
        float4 acc = {0.f, 0.f, 0.f, 0.f};
        for (int i = 0; i < n; ++i) {
            const float wgt = s_act_w[i];
            const float4 rr = *(const float4*)(w_emb + (size_t)s_act_id[i] * EE + 4 * t);
            acc.x += wgt * rr.x; acc.y += wgt * rr.y;
            acc.z += wgt * rr.z; acc.w += wgt * rr.w;
        }
        acc.x *= gate; acc.y *= gate; acc.z *= gate; acc.w *= gate;
        *(float4*)(out + b * EE + 4 * t) = acc;
    }
}

// ---------------------------------------------------------------------------
extern "C" void kernel_launch(void* const* d_in, const int* in_sizes, int n_in,
                              void* d_out, int out_size, void* d_ws, size_t ws_size,
                              hipStream_t stream) {
    const int* inputs = (const int*)d_in[0];
    const float* w_emb = (const float*)d_in[1];
    const float* a_emb = (const float*)d_in[2];
    const float* a_weight = (const float*)d_in[3];
    float* out = (float*)d_out;
    float* cent = (float*)d_ws;  // 50000 floats = 200 KB scratch

    cent_kernel<<<(VV + 63) / 64, 256, 0, stream>>>(w_emb, a_emb, a_weight, cent);
    row_kernel<<<BB, 256, 0, stream>>>(inputs, w_emb, cent, out);
}